// Round 14
// baseline (132.336 us; speedup 1.0000x reference)
//
#include <hip/hip_runtime.h>
#include <hip/hip_bf16.h>

using short8 = __attribute__((ext_vector_type(8))) short;
using f32x4  = __attribute__((ext_vector_type(4))) float;
using f32x16 = __attribute__((ext_vector_type(16))) float;
using uint2v = __attribute__((ext_vector_type(2))) unsigned;

#define B_  4
#define KD  128      // head dim / model dim k
#define T_  2048
#define H_  8
#define HK  (H_*KD)  // 1024
#define NT  (T_/64)  // 32 KV tiles
#define VROW 72      // padded fp8 V row bytes (odd dword-pair stride -> conflict-free)

__device__ __forceinline__ ushort f2bf(float f) {
    unsigned u = __builtin_bit_cast(unsigned, f);
    u += 0x7fffu + ((u >> 16) & 1u);
    return (ushort)(u >> 16);
}

// raw v_exp_f32: computes 2^x in one instruction (args here are finite, |x| small)
__device__ __forceinline__ float exp2_hw(float x) {
    float r;
    asm("v_exp_f32 %0, %1" : "=v"(r) : "v"(x));
    return r;
}

// packs 2 f32 -> 2 fp8 e4m3 into low / high 16 bits of r (other bits preserved)
__device__ __forceinline__ unsigned cvt_pk_fp8_lo(unsigned old, float a, float b) {
    unsigned r = old;
    asm("v_cvt_pk_fp8_f32 %0, %1, %2" : "+v"(r) : "v"(a), "v"(b));
    return r;
}
__device__ __forceinline__ unsigned cvt_pk_fp8_hi(unsigned old, float a, float b) {
    unsigned r = old;
    asm("v_cvt_pk_fp8_f32 %0, %1, %2 op_sel:[0,0,1]" : "+v"(r) : "v"(a), "v"(b));
    return r;
}

// Fused prep: blocks [0,2048) convert the 4 weight mats (contiguous dst),
// blocks [2048,2304) transpose x [B][KD][T] f32 -> xt [B][T][KD] bf16.
__global__ __launch_bounds__(256) void prep_kernel(const float* __restrict__ x,
                                                   const float* __restrict__ Wq,
                                                   const float* __restrict__ Wk,
                                                   const float* __restrict__ Wv,
                                                   const float* __restrict__ Wu,
                                                   ushort* __restrict__ wdst,
                                                   ushort* __restrict__ xt) {
    __shared__ float tile[64][65];
    int bx = blockIdx.x;
    if (bx < 2048) {
        int i = bx * 256 + threadIdx.x;
        const int n1 = HK * KD;
        const float* src = (i < n1) ? Wq : (i < 2*n1) ? Wk : (i < 3*n1) ? Wv : Wu;
        wdst[i] = f2bf(src[i & (n1 - 1)]);
        return;
    }
    int bi = bx - 2048;
    int t0 = (bi & 31) * 64;
    int k0 = ((bi >> 5) & 1) * 64;
    int b  = bi >> 6;
    int c  = threadIdx.x & 63;
    int r4 = threadIdx.x >> 6;
    #pragma unroll
    for (int i = 0; i < 16; i++) {
        int k = r4 * 16 + i;
        tile[k][c] = x[((size_t)b * KD + k0 + k) * T_ + t0 + c];
    }
    __syncthreads();
    #pragma unroll
    for (int i = 0; i < 16; i++) {
        int t = r4 * 16 + i;
        xt[((size_t)b * T_ + t0 + t) * KD + k0 + c] = f2bf(tile[c][t]);
    }
}

// Fused projections, packed-store epilogues (r11-verified).
// Q scale folds 1/sqrt(128) * log2(e) so attention softmax runs in base 2.
__global__ __launch_bounds__(256, 2) void proj_kernel(const ushort* __restrict__ xt,
                                                      const ushort* __restrict__ wall,
                                                      ushort* __restrict__ qtb,
                                                      ushort* __restrict__ ktb,
                                                      unsigned char* __restrict__ vsb) {
    int bz = blockIdx.y;
    int which = bz >> 2, b = bz & 3;
    int tidb = blockIdx.x;                 // 0..127
    int lane = threadIdx.x & 63;
    int w    = threadIdx.x >> 6;
    int lq = lane & 31, hi = lane >> 5, hi8 = hi * 8;

    int tt0 = (tidb >> 3) * 128;           // t-tile base (16 tiles)
    int jj0 = (tidb & 7) * 128;            // j-tile base (8 tiles)

    const ushort *a0p, *a1p, *b0p, *b1p;
    int m0, n0;                            // m = D-row base, n = D-col base
    if (which < 2) {
        m0 = jj0 + (w >> 1) * 64;          // rows = j
        n0 = tt0 + (w & 1) * 64;           // cols = t
        const ushort* A  = wall + (size_t)which * (HK * KD);
        const ushort* Bp = xt + (size_t)b * T_ * KD;
        a0p = A  + (size_t)(m0 + lq) * KD + hi8;
        a1p = A  + (size_t)(m0 + 32 + lq) * KD + hi8;
        b0p = Bp + (size_t)(n0 + lq) * KD + hi8;
        b1p = Bp + (size_t)(n0 + 32 + lq) * KD + hi8;
    } else {
        m0 = tt0 + (w >> 1) * 64;          // rows = t
        n0 = jj0 + (w & 1) * 64;           // cols = j
        const ushort* A  = xt + (size_t)b * T_ * KD;
        const ushort* Bp = wall + (size_t)2 * (HK * KD);
        a0p = A  + (size_t)(m0 + lq) * KD + hi8;
        a1p = A  + (size_t)(m0 + 32 + lq) * KD + hi8;
        b0p = Bp + (size_t)(n0 + lq) * KD + hi8;
        b1p = Bp + (size_t)(n0 + 32 + lq) * KD + hi8;
    }

    short8 a0[8], a1[8], b0[8], b1[8];
    #pragma unroll
    for (int kc = 0; kc < 8; kc++) {
        a0[kc] = *(const short8*)(a0p + kc * 16);
        a1[kc] = *(const short8*)(a1p + kc * 16);
        b0[kc] = *(const short8*)(b0p + kc * 16);
        b1[kc] = *(const short8*)(b1p + kc * 16);
    }
    f32x16 acc[2][2] = {};
    #pragma unroll
    for (int kc = 0; kc < 8; kc++) {
        acc[0][0] = __builtin_amdgcn_mfma_f32_32x32x16_bf16(a0[kc], b0[kc], acc[0][0], 0, 0, 0);
        acc[0][1] = __builtin_amdgcn_mfma_f32_32x32x16_bf16(a0[kc], b1[kc], acc[0][1], 0, 0, 0);
        acc[1][0] = __builtin_amdgcn_mfma_f32_32x32x16_bf16(a1[kc], b0[kc], acc[1][0], 0, 0, 0);
        acc[1][1] = __builtin_amdgcn_mfma_f32_32x32x16_bf16(a1[kc], b1[kc], acc[1][1], 0, 0, 0);
    }

    if (which < 2) {
        // Q: 1/sqrt(128) * log2(e)  (base-2 softmax in attn);  K: 1.0
        float scale = which ? 1.f : 0.12751743f;
        ushort* C = (which ? ktb : qtb) + (size_t)b * T_ * HK;
        #pragma unroll
        for (int i = 0; i < 2; i++)
            #pragma unroll
            for (int jj = 0; jj < 2; jj++) {
                int t = n0 + jj*32 + lq;
                #pragma unroll
                for (int qd = 0; qd < 4; qd++) {
                    int jb = m0 + i*32 + 8*qd + 4*hi;
                    const f32x16& a = acc[i][jj];
                    unsigned u0 = (unsigned)f2bf(a[4*qd+0]*scale)
                                | ((unsigned)f2bf(a[4*qd+1]*scale) << 16);
                    unsigned u1 = (unsigned)f2bf(a[4*qd+2]*scale)
                                | ((unsigned)f2bf(a[4*qd+3]*scale) << 16);
                    uint2v uv; uv[0] = u0; uv[1] = u1;
                    *(uint2v*)(C + (size_t)t * HK + jb) = uv;
                }
            }
    } else {
        unsigned char* C = vsb + (size_t)b * HK * T_;
        #pragma unroll
        for (int i = 0; i < 2; i++)
            #pragma unroll
            for (int jj = 0; jj < 2; jj++) {
                int j = n0 + jj*32 + lq;
                #pragma unroll
                for (int qd = 0; qd < 4; qd++) {
                    int tb = m0 + i*32 + 8*qd + 4*hi;
                    const f32x16& a = acc[i][jj];
                    unsigned dw = cvt_pk_fp8_lo(0u, a[4*qd+0], a[4*qd+1]);
                    dw = cvt_pk_fp8_hi(dw, a[4*qd+2], a[4*qd+3]);
                    *(unsigned*)(C + (size_t)j * T_ + tb) = dw;
                }
            }
    }
}

// out[m][n] = sum_k A[m][k]*B[n][k] + bias[m];  f32 out  (r6-verified version)
__global__ __launch_bounds__(256) void gemm_abT_f32bias(const ushort* __restrict__ A,
                                                        const ushort* __restrict__ B, long sB,
                                                        const float* __restrict__ bias,
                                                        float* __restrict__ C, long sC,
                                                        int M, int N, int Kd) {
    int b = blockIdx.z;
    B += (long)b * sB;  C += (long)b * sC;
    int lane = threadIdx.x & 63;
    int w    = threadIdx.x >> 6;
    int lr = lane & 15, lg = lane >> 4;
    int m0 = blockIdx.x * 64 + (w >> 1) * 32;
    int n0 = blockIdx.y * 64 + (w & 1) * 32;

    f32x4 acc[2][2] = {};
    #pragma unroll 4
    for (int k0 = 0; k0 < Kd; k0 += 32) {
        short8 af[2], bf[2];
        #pragma unroll
        for (int i = 0; i < 2; i++)
            af[i] = *(const short8*)(A + (long)(m0 + i*16 + lr) * Kd + k0 + lg*8);
        #pragma unroll
        for (int j = 0; j < 2; j++)
            bf[j] = *(const short8*)(B + (long)(n0 + j*16 + lr) * Kd + k0 + lg*8);
        #pragma unroll
        for (int i = 0; i < 2; i++)
            #pragma unroll
            for (int j = 0; j < 2; j++)
                acc[i][j] = __builtin_amdgcn_mfma_f32_16x16x32_bf16(af[i], bf[j], acc[i][j], 0, 0, 0);
    }
    #pragma unroll
    for (int i = 0; i < 2; i++)
        #pragma unroll
        for (int j = 0; j < 2; j++)
            #pragma unroll
            for (int r = 0; r < 4; r++) {
                int m = m0 + i*16 + lg*4 + r;
                int n = n0 + j*16 + lr;
                C[(long)m * N + n] = acc[i][j][r] + bias[m];
            }
}

// Flash attention: 4 waves x 32 queries (128 q/block), grid 512 -> 2 blocks/CU
// (independent barriers -> cross-block MFMA/VALU/LDS co-scheduling). Same
// r13-verified dataflow: K bf16 LDS (XOR swizzle) + V fp8 LDS (72B pad),
// double-buffered, reg-staged async; swapped QK^T bf16; base-2 softmax via
// v_exp_f32; fp8 P cvt_pk+permlane; PV fp8 MFMA; defer-max THR=7.
__global__ __launch_bounds__(256, 2) void attn32_kernel(const ushort* __restrict__ qt,
                                                        const ushort* __restrict__ kt,
                                                        const unsigned char* __restrict__ vs,
                                                        ushort* __restrict__ ot) {
    int f = blockIdx.x;
    int xcd = f & 7, u = f >> 3;
    int qt16 = u & 15, gh = u >> 4;        // 16 q-tiles of 128 per (b,h)
    int g = xcd + 8 * gh;                  // 0..31 == h + 8*b
    int h = g & 7, b = g >> 3;
    int w    = threadIdx.x >> 6;           // 0..3
    int lane = threadIdx.x & 63;
    int lq = lane & 31, hi = lane >> 5;
    int hi8 = hi * 8;
    int q0w = qt16 * 128 + w * 32;

    __shared__ __align__(16) ushort k_lds[2][64 * 128];
    __shared__ __align__(16) unsigned char v_lds[2][128 * VROW];

    int tid = threadIdx.x;
    // K staging: 256 threads, row kr, elem cols [kc0, kc0+32)
    int kr = tid >> 2, kc0 = (tid & 3) << 5;
    const ushort* kst = kt + ((size_t)b * T_ + kr) * HK + h * KD + kc0;
    int ksw = (kr & 7) << 3;
    int kwi[4];
    #pragma unroll
    for (int j = 0; j < 4; j++)
        kwi[j] = kr * 128 + ((kc0 + j*8) ^ ksw);
    // V staging (fp8): 256 threads, row vrow, byte cols [vc0b, vc0b+32)
    int vrow = tid >> 1, vc0b = (tid & 1) << 5;
    const unsigned char* vst = vs + ((size_t)b * HK + h * KD + vrow) * T_ + vc0b;
    int c4b = vc0b >> 4, vswz = vrow & 3;
    int vwb[2];
    #pragma unroll
    for (int j = 0; j < 2; j++)
        vwb[j] = vrow * VROW + (((c4b + j) ^ vswz) << 4);

    const ushort* qbase = qt + ((size_t)b * T_ + q0w + lq) * HK + h * KD + hi8;

    short8 qf[8];
    #pragma unroll
    for (int dc = 0; dc < 8; dc++)
        qf[dc] = *(const short8*)(qbase + dc * 16);

    // prologue: stage tile 0, issue loads for tile 1
    short8 rk[4];
    long rv[4];
    #pragma unroll
    for (int j = 0; j < 4; j++) {
        rk[j] = *(const short8*)(kst + j*8);
        rv[j] = *(const long*)(vst + j*8);
    }
    #pragma unroll
    for (int j = 0; j < 4; j++)
        *(short8*)&k_lds[0][kwi[j]] = rk[j];
    #pragma unroll
    for (int j = 0; j < 2; j++) {
        *(long*)&v_lds[0][vwb[j]]     = rv[2*j];
        *(long*)&v_lds[0][vwb[j] + 8] = rv[2*j + 1];
    }
    #pragma unroll
    for (int j = 0; j < 4; j++) {
        rk[j] = *(const short8*)(kst + (size_t)64 * HK + j*8);
        rv[j] = *(const long*)(vst + 64 + j*8);
    }
    __syncthreads();

    f32x16 o_acc[4] = {};
    float m_q = -1e30f, l_q = 0.f;
    const int xsw = (lq & 7) << 3;      // K read swizzle (bf16 elems)
    const int vsw = lq & 3;             // V read chunk swizzle

    for (int t = 0; t < NT; ++t) {
        const int cur = t & 1;
        f32x16 s0 = {}, s1 = {};
        const ushort* kr0 = &k_lds[cur][(size_t)lq * 128];
        const ushort* kr1 = &k_lds[cur][(size_t)(32 + lq) * 128];
        #pragma unroll
        for (int dc = 0; dc < 8; dc++) {
            int c = (dc * 16 + hi8) ^ xsw;
            short8 kf0 = *(const short8*)(kr0 + c);
            short8 kf1 = *(const short8*)(kr1 + c);
            s0 = __builtin_amdgcn_mfma_f32_32x32x16_bf16(kf0, qf[dc], s0, 0, 0, 0);
            s1 = __builtin_amdgcn_mfma_f32_32x32x16_bf16(kf1, qf[dc], s1, 0, 0, 0);
        }

        float mx[8];
        #pragma unroll
        for (int i = 0; i < 8; i++)
            mx[i] = fmaxf(fmaxf(s0[i], s0[i+8]), fmaxf(s1[i], s1[i+8]));
        #pragma unroll
        for (int st = 4; st > 0; st >>= 1)
            #pragma unroll
            for (int i = 0; i < st; i++) mx[i] = fmaxf(mx[i], mx[i+st]);
        float pmax = fmaxf(mx[0], __shfl_xor(mx[0], 32));

        if (!__all(pmax - m_q <= 7.f)) {      // base-2: P <= 2^7 = 128 < 448
            float mnew = fmaxf(m_q, pmax);
            float corr = exp2_hw(m_q - mnew);
            l_q *= corr;
            m_q = mnew;
            #pragma unroll
            for (int r = 0; r < 16; r++) {
                float cr = __shfl(corr, (r & 3) + 8 * (r >> 2) + 4 * hi);
                #pragma unroll
                for (int dn = 0; dn < 4; dn++) o_acc[dn][r] *= cr;
            }
        }

        float ls0 = 0.f, ls1 = 0.f, ls2 = 0.f, ls3 = 0.f;
        #pragma unroll
        for (int r = 0; r < 16; r++) {
            float e0 = exp2_hw(s0[r] - m_q);
            float e1 = exp2_hw(s1[r] - m_q);
            s0[r] = e0; s1[r] = e1;
            if (r & 1) { ls1 += e0; ls3 += e1; } else { ls0 += e0; ls2 += e1; }
        }
        float lsum = (ls0 + ls1) + (ls2 + ls3);
        lsum += __shfl_xor(lsum, 32);
        l_q += lsum;

        // ---- pack P -> fp8 + permlane redistribute (r10-verified) ----
        long ap8[4];
        #pragma unroll
        for (int ks = 0; ks < 4; ks++) {
            const f32x16& sN = (ks < 2) ? s0 : s1;
            int rb = (ks & 1) * 8;
            unsigned F0 = cvt_pk_fp8_lo(0u, sN[rb+0], sN[rb+1]);
            F0 = cvt_pk_fp8_hi(F0, sN[rb+2], sN[rb+3]);
            unsigned F1 = cvt_pk_fp8_lo(0u, sN[rb+4], sN[rb+5]);
            F1 = cvt_pk_fp8_hi(F1, sN[rb+6], sN[rb+7]);
            uint2v d01 = __builtin_amdgcn_permlane32_swap(F0, F1, false, false);
            ap8[ks] = (long)(((unsigned long)d01[1] << 32) | (unsigned long)d01[0]);
        }

        // ---- O += P V from fp8 v_lds[cur] ----
        #pragma unroll
        for (int dn = 0; dn < 4; dn++) {
            const unsigned char* vr = &v_lds[cur][(size_t)(dn*32 + lq) * VROW];
            #pragma unroll
            for (int ks = 0; ks < 4; ks++) {
                long vf = *(const long*)(vr + ((ks ^ vsw) << 4) + hi8);
                o_acc[dn] = __builtin_amdgcn_mfma_f32_32x32x16_fp8_fp8(ap8[ks], vf, o_acc[dn], 0, 0, 0);
            }
        }

        __syncthreads();
        if (t + 1 < NT) {
            const int nxt = cur ^ 1;
            #pragma unroll
            for (int j = 0; j < 4; j++)
                *(short8*)&k_lds[nxt][kwi[j]] = rk[j];
            #pragma unroll
            for (int j = 0; j < 2; j++) {
                *(long*)&v_lds[nxt][vwb[j]]     = rv[2*j];
                *(long*)&v_lds[nxt][vwb[j] + 8] = rv[2*j + 1];
            }
            if (t + 2 < NT) {
                size_t ko = (size_t)(t + 2) * 64 * HK;
                int    vo = (t + 2) * 64;
                #pragma unroll
                for (int j = 0; j < 4; j++) {
                    rk[j] = *(const short8*)(kst + ko + j*8);
                    rv[j] = *(const long*)(vst + vo + j*8);
                }
            }
            __syncthreads();
        }
    }

    float linv = 1.f / l_q;
    ushort* ob = ot + ((size_t)b * T_ + q0w) * HK + h * KD;
    #pragma unroll
    for (int r = 0; r < 16; r++) {
        int qrow = (r & 3) + 8 * (r >> 2) + 4 * hi;
        float lr_ = __shfl(linv, qrow);
        #pragma unroll
        for (int dn = 0; dn < 4; dn++)
            ob[(size_t)qrow * HK + dn*32 + lq] = f2bf(o_acc[dn][r] * lr_);
    }
}

extern "C" void kernel_launch(void* const* d_in, const int* in_sizes, int n_in,
                              void* d_out, int out_size, void* d_ws, size_t ws_size,
                              hipStream_t stream) {
    const float* x  = (const float*)d_in[0];
    const float* Wq = (const float*)d_in[1];
    const float* Wk = (const float*)d_in[2];
    const float* Wv = (const float*)d_in[3];
    const float* Wu = (const float*)d_in[4];
    const float* bu = (const float*)d_in[5];
    float* out = (float*)d_out;

    const size_t XT  = (size_t)B_ * T_ * KD * 2;
    const size_t WB  = (size_t)HK * KD * 2;
    const size_t BIG = (size_t)B_ * T_ * HK * 2;   // bf16 buffers
    const size_t VSZ = (size_t)B_ * HK * T_;       // fp8 V
    size_t need = XT + 4*WB + 3*BIG + VSZ;
    if (ws_size < need) return;

    char* p = (char*)d_ws;
    ushort* xt  = (ushort*)p;            p += XT;
    ushort* wqb = (ushort*)p;            p += WB;   // wq|wk|wv|wu contiguous
    ushort* wkb = (ushort*)p;            p += WB;
    ushort* wvb = (ushort*)p;            p += WB;
    ushort* wub = (ushort*)p;            p += WB;
    ushort* qtb = (ushort*)p;            p += BIG;
    ushort* ktb = (ushort*)p;            p += BIG;
    unsigned char* vsb = (unsigned char*)p;  p += VSZ;
    ushort* otb = (ushort*)p;            p += BIG;
    (void)wkb; (void)wvb;

    prep_kernel<<<2304, 256, 0, stream>>>(x, Wq, Wk, Wv, Wu, wqb, xt);

    proj_kernel<<<dim3(128, 12), 256, 0, stream>>>(xt, wqb, qtb, ktb, vsb);

    attn32_kernel<<<dim3(512), 256, 0, stream>>>(qtb, ktb, vsb, otb);

    gemm_abT_f32bias<<<dim3(KD/64, T_/64, B_), 256, 0, stream>>>(
        wub, otb, (long)T_*HK, bu, out, (long)KD*T_, KD, T_, HK);
}

// Round 15
// 129.583 us; speedup vs baseline: 1.0212x; 1.0212x over previous
//
#include <hip/hip_runtime.h>
#include <hip/hip_bf16.h>

using short8 = __attribute__((ext_vector_type(8))) short;
using f32x4  = __attribute__((ext_vector_type(4))) float;
using f32x16 = __attribute__((ext_vector_type(16))) float;
using uint2v = __attribute__((ext_vector_type(2))) unsigned;

#define B_  4
#define KD  128      // head dim / model dim k
#define T_  2048
#define H_  8
#define HK  (H_*KD)  // 1024
#define NT  (T_/64)  // 32 KV tiles
#define VROW 72      // padded fp8 V row bytes (odd dword-pair stride -> conflict-free)

typedef const __attribute__((address_space(1))) char glob_char;
typedef __attribute__((address_space(3))) char lds_char;

__device__ __forceinline__ ushort f2bf(float f) {
    unsigned u = __builtin_bit_cast(unsigned, f);
    u += 0x7fffu + ((u >> 16) & 1u);
    return (ushort)(u >> 16);
}

// raw v_exp_f32: computes 2^x in one instruction (args here are finite, |x| small)
__device__ __forceinline__ float exp2_hw(float x) {
    float r;
    asm("v_exp_f32 %0, %1" : "=v"(r) : "v"(x));
    return r;
}

// packs 2 f32 -> 2 fp8 e4m3 into low / high 16 bits of r (other bits preserved)
__device__ __forceinline__ unsigned cvt_pk_fp8_lo(unsigned old, float a, float b) {
    unsigned r = old;
    asm("v_cvt_pk_fp8_f32 %0, %1, %2" : "+v"(r) : "v"(a), "v"(b));
    return r;
}
__device__ __forceinline__ unsigned cvt_pk_fp8_hi(unsigned old, float a, float b) {
    unsigned r = old;
    asm("v_cvt_pk_fp8_f32 %0, %1, %2 op_sel:[0,0,1]" : "+v"(r) : "v"(a), "v"(b));
    return r;
}

// Fused prep: blocks [0,2048) convert the 4 weight mats (contiguous dst),
// blocks [2048,2304) transpose x [B][KD][T] f32 -> xt [B][T][KD] bf16.
__global__ __launch_bounds__(256) void prep_kernel(const float* __restrict__ x,
                                                   const float* __restrict__ Wq,
                                                   const float* __restrict__ Wk,
                                                   const float* __restrict__ Wv,
                                                   const float* __restrict__ Wu,
                                                   ushort* __restrict__ wdst,
                                                   ushort* __restrict__ xt) {
    __shared__ float tile[64][65];
    int bx = blockIdx.x;
    if (bx < 2048) {
        int i = bx * 256 + threadIdx.x;
        const int n1 = HK * KD;
        const float* src = (i < n1) ? Wq : (i < 2*n1) ? Wk : (i < 3*n1) ? Wv : Wu;
        wdst[i] = f2bf(src[i & (n1 - 1)]);
        return;
    }
    int bi = bx - 2048;
    int t0 = (bi & 31) * 64;
    int k0 = ((bi >> 5) & 1) * 64;
    int b  = bi >> 6;
    int c  = threadIdx.x & 63;
    int r4 = threadIdx.x >> 6;
    #pragma unroll
    for (int i = 0; i < 16; i++) {
        int k = r4 * 16 + i;
        tile[k][c] = x[((size_t)b * KD + k0 + k) * T_ + t0 + c];
    }
    __syncthreads();
    #pragma unroll
    for (int i = 0; i < 16; i++) {
        int t = r4 * 16 + i;
        xt[((size_t)b * T_ + t0 + t) * KD + k0 + c] = f2bf(tile[c][t]);
    }
}

// Fused projections, packed-store epilogues (r11-verified), XCD-chunked tidb.
// Q scale folds 1/sqrt(128) * log2(e) so attention softmax runs in base 2.
__global__ __launch_bounds__(256, 2) void proj_kernel(const ushort* __restrict__ xt,
                                                      const ushort* __restrict__ wall,
                                                      ushort* __restrict__ qtb,
                                                      ushort* __restrict__ ktb,
                                                      unsigned char* __restrict__ vsb) {
    int bz = blockIdx.y;
    int which = bz >> 2, b = bz & 3;
    int bxr = blockIdx.x;                  // 0..127
    int tidb = (bxr & 7) * 16 + (bxr >> 3);   // XCD chunk swizzle (bijective)
    int lane = threadIdx.x & 63;
    int w    = threadIdx.x >> 6;
    int lq = lane & 31, hi = lane >> 5, hi8 = hi * 8;

    int tt0 = (tidb >> 3) * 128;           // t-tile base (16 tiles)
    int jj0 = (tidb & 7) * 128;            // j-tile base (8 tiles)

    const ushort *a0p, *a1p, *b0p, *b1p;
    int m0, n0;                            // m = D-row base, n = D-col base
    if (which < 2) {
        m0 = jj0 + (w >> 1) * 64;          // rows = j
        n0 = tt0 + (w & 1) * 64;           // cols = t
        const ushort* A  = wall + (size_t)which * (HK * KD);
        const ushort* Bp = xt + (size_t)b * T_ * KD;
        a0p = A  + (size_t)(m0 + lq) * KD + hi8;
        a1p = A  + (size_t)(m0 + 32 + lq) * KD + hi8;
        b0p = Bp + (size_t)(n0 + lq) * KD + hi8;
        b1p = Bp + (size_t)(n0 + 32 + lq) * KD + hi8;
    } else {
        m0 = tt0 + (w >> 1) * 64;          // rows = t
        n0 = jj0 + (w & 1) * 64;           // cols = j
        const ushort* A  = xt + (size_t)b * T_ * KD;
        const ushort* Bp = wall + (size_t)2 * (HK * KD);
        a0p = A  + (size_t)(m0 + lq) * KD + hi8;
        a1p = A  + (size_t)(m0 + 32 + lq) * KD + hi8;
        b0p = Bp + (size_t)(n0 + lq) * KD + hi8;
        b1p = Bp + (size_t)(n0 + 32 + lq) * KD + hi8;
    }

    short8 a0[8], a1[8], b0[8], b1[8];
    #pragma unroll
    for (int kc = 0; kc < 8; kc++) {
        a0[kc] = *(const short8*)(a0p + kc * 16);
        a1[kc] = *(const short8*)(a1p + kc * 16);
        b0[kc] = *(const short8*)(b0p + kc * 16);
        b1[kc] = *(const short8*)(b1p + kc * 16);
    }
    f32x16 acc[2][2] = {};
    #pragma unroll
    for (int kc = 0; kc < 8; kc++) {
        acc[0][0] = __builtin_amdgcn_mfma_f32_32x32x16_bf16(a0[kc], b0[kc], acc[0][0], 0, 0, 0);
        acc[0][1] = __builtin_amdgcn_mfma_f32_32x32x16_bf16(a0[kc], b1[kc], acc[0][1], 0, 0, 0);
        acc[1][0] = __builtin_amdgcn_mfma_f32_32x32x16_bf16(a1[kc], b0[kc], acc[1][0], 0, 0, 0);
        acc[1][1] = __builtin_amdgcn_mfma_f32_32x32x16_bf16(a1[kc], b1[kc], acc[1][1], 0, 0, 0);
    }

    if (which < 2) {
        // Q: 1/sqrt(128) * log2(e)  (base-2 softmax in attn);  K: 1.0
        float scale = which ? 1.f : 0.12751743f;
        ushort* C = (which ? ktb : qtb) + (size_t)b * T_ * HK;
        #pragma unroll
        for (int i = 0; i < 2; i++)
            #pragma unroll
            for (int jj = 0; jj < 2; jj++) {
                int t = n0 + jj*32 + lq;
                #pragma unroll
                for (int qd = 0; qd < 4; qd++) {
                    int jb = m0 + i*32 + 8*qd + 4*hi;
                    const f32x16& a = acc[i][jj];
                    unsigned u0 = (unsigned)f2bf(a[4*qd+0]*scale)
                                | ((unsigned)f2bf(a[4*qd+1]*scale) << 16);
                    unsigned u1 = (unsigned)f2bf(a[4*qd+2]*scale)
                                | ((unsigned)f2bf(a[4*qd+3]*scale) << 16);
                    uint2v uv; uv[0] = u0; uv[1] = u1;
                    *(uint2v*)(C + (size_t)t * HK + jb) = uv;
                }
            }
    } else {
        unsigned char* C = vsb + (size_t)b * HK * T_;
        #pragma unroll
        for (int i = 0; i < 2; i++)
            #pragma unroll
            for (int jj = 0; jj < 2; jj++) {
                int j = n0 + jj*32 + lq;
                #pragma unroll
                for (int qd = 0; qd < 4; qd++) {
                    int tb = m0 + i*32 + 8*qd + 4*hi;
                    const f32x16& a = acc[i][jj];
                    unsigned dw = cvt_pk_fp8_lo(0u, a[4*qd+0], a[4*qd+1]);
                    dw = cvt_pk_fp8_hi(dw, a[4*qd+2], a[4*qd+3]);
                    *(unsigned*)(C + (size_t)j * T_ + tb) = dw;
                }
            }
    }
}

// out[m][n] = sum_k A[m][k]*B[n][k] + bias[m];  f32 out  (r6-verified version)
__global__ __launch_bounds__(256) void gemm_abT_f32bias(const ushort* __restrict__ A,
                                                        const ushort* __restrict__ B, long sB,
                                                        const float* __restrict__ bias,
                                                        float* __restrict__ C, long sC,
                                                        int M, int N, int Kd) {
    int b = blockIdx.z;
    B += (long)b * sB;  C += (long)b * sC;
    int lane = threadIdx.x & 63;
    int w    = threadIdx.x >> 6;
    int lr = lane & 15, lg = lane >> 4;
    int m0 = blockIdx.x * 64 + (w >> 1) * 32;
    int n0 = blockIdx.y * 64 + (w & 1) * 32;

    f32x4 acc[2][2] = {};
    #pragma unroll 4
    for (int k0 = 0; k0 < Kd; k0 += 32) {
        short8 af[2], bf[2];
        #pragma unroll
        for (int i = 0; i < 2; i++)
            af[i] = *(const short8*)(A + (long)(m0 + i*16 + lr) * Kd + k0 + lg*8);
        #pragma unroll
        for (int j = 0; j < 2; j++)
            bf[j] = *(const short8*)(B + (long)(n0 + j*16 + lr) * Kd + k0 + lg*8);
        #pragma unroll
        for (int i = 0; i < 2; i++)
            #pragma unroll
            for (int j = 0; j < 2; j++)
                acc[i][j] = __builtin_amdgcn_mfma_f32_16x16x32_bf16(af[i], bf[j], acc[i][j], 0, 0, 0);
    }
    #pragma unroll
    for (int i = 0; i < 2; i++)
        #pragma unroll
        for (int j = 0; j < 2; j++)
            #pragma unroll
            for (int r = 0; r < 4; r++) {
                int m = m0 + i*16 + lg*4 + r;
                int n = n0 + j*16 + lr;
                C[(long)m * N + n] = acc[i][j][r] + bias[m];
            }
}

// Flash attention (r13 structure, K staged via global_load_lds DMA):
// 8 waves x 32 queries, grid 256. K bf16 LDS with XOR swizzle realized by
// pre-swizzled per-lane global source (LDS dest linear per wave, layout
// bit-identical to r13). V fp8 LDS (72B pad) reg-staged. Double-buffered,
// SINGLE barrier per tile (r9-verified disjointness). Swapped QK^T bf16,
// base-2 softmax via v_exp_f32, fp8 P cvt_pk+permlane, PV fp8 MFMA, THR=7.
__global__ __launch_bounds__(512, 2) void attn32_kernel(const ushort* __restrict__ qt,
                                                        const ushort* __restrict__ kt,
                                                        const unsigned char* __restrict__ vs,
                                                        ushort* __restrict__ ot) {
    int f = blockIdx.x;
    int xcd = f & 7, u = f >> 3;
    int qt8 = u & 7, gh = u >> 3;
    int g = xcd + 8 * gh;                  // 0..31 == h + 8*b
    int h = g & 7, b = g >> 3;
    int w    = threadIdx.x >> 6;
    int lane = threadIdx.x & 63;
    int lq = lane & 31, hi = lane >> 5;
    int hi8 = hi * 8;
    int q0w = qt8 * 256 + w * 32;

    __shared__ __align__(16) ushort k_lds[2][64 * 128];
    __shared__ __align__(16) unsigned char v_lds[2][128 * VROW];

    int tid  = threadIdx.x;
    // ---- K DMA constants: wave w, instr i covers LDS bytes [(w*2+i)*1024, +1024)
    // row_i = w*8 + i*4 + (lane>>4), chunk p = lane&15, src chunk = p ^ (row&7)
    const char* kgb = (const char*)(kt + ((size_t)b * T_) * HK + h * KD);
    int krow_base = w * 8 + (lane >> 4);       // +4 for i=1
    int kp = lane & 15;
    size_t ksrc0 = (size_t)krow_base * (HK * 2) + (size_t)((kp ^ (krow_base & 7)) << 4);
    int krow1 = krow_base + 4;
    size_t ksrc1 = (size_t)krow1 * (HK * 2) + (size_t)((kp ^ (krow1 & 7)) << 4);

    // V staging: 512 threads x 16B; row = d (0..127), 16B chunk = tid&3
    int vrow = tid >> 2, vc16 = (tid & 3) << 4;
    const unsigned char* vst = vs + ((size_t)b * HK + h * KD + vrow) * T_ + vc16;
    int vwb = vrow * VROW + ((((vc16 >> 4) ^ (vrow & 3))) << 4);

    const ushort* qbase = qt + ((size_t)b * T_ + q0w + lq) * HK + h * KD + hi8;

    short8 qf[8];
    #pragma unroll
    for (int dc = 0; dc < 8; dc++)
        qf[dc] = *(const short8*)(qbase + dc * 16);

    // prologue: DMA K tile 0 -> buf0; V tile 0 -> buf0 (reg), load rv(1)
    {
        glob_char* g0 = (glob_char*)(kgb + ksrc0);
        glob_char* g1 = (glob_char*)(kgb + ksrc1);
        lds_char* d0 = (lds_char*)((char*)&k_lds[0][0] + (w*2 + 0) * 1024);
        lds_char* d1 = (lds_char*)((char*)&k_lds[0][0] + (w*2 + 1) * 1024);
        __builtin_amdgcn_global_load_lds(g0, d0, 16, 0, 0);
        __builtin_amdgcn_global_load_lds(g1, d1, 16, 0, 0);
    }
    long rvlo = *(const long*)(vst);
    long rvhi = *(const long*)(vst + 8);
    *(long*)&v_lds[0][vwb]       = rvlo;
    *(long*)&v_lds[0][vwb + 8]   = rvhi;
    rvlo = *(const long*)(vst + 64);
    rvhi = *(const long*)(vst + 64 + 8);
    __syncthreads();

    f32x16 o_acc[4] = {};
    float m_q = -1e30f, l_q = 0.f;
    const int xsw = (lq & 7) << 3;      // K read swizzle (bf16 elems)
    const int vsw = lq & 3;             // V read chunk swizzle

    for (int t = 0; t < NT; ++t) {
        const int cur = t & 1;
        const int nxt = cur ^ 1;
        // ---- issue K DMA for tile t+1 into k_lds[nxt] (overlaps whole tile) ----
        if (t + 1 < NT) {
            size_t tb = (size_t)(t + 1) * 64 * (HK * 2);
            glob_char* g0 = (glob_char*)(kgb + tb + ksrc0);
            glob_char* g1 = (glob_char*)(kgb + tb + ksrc1);
            lds_char* d0 = (lds_char*)((char*)&k_lds[nxt][0] + (w*2 + 0) * 1024);
            lds_char* d1 = (lds_char*)((char*)&k_lds[nxt][0] + (w*2 + 1) * 1024);
            __builtin_amdgcn_global_load_lds(g0, d0, 16, 0, 0);
            __builtin_amdgcn_global_load_lds(g1, d1, 16, 0, 0);
        }

        // ---- QK^T from k_lds[cur] ----
        f32x16 s0 = {}, s1 = {};
        const ushort* kr0 = &k_lds[cur][(size_t)lq * 128];
        const ushort* kr1 = &k_lds[cur][(size_t)(32 + lq) * 128];
        #pragma unroll
        for (int dc = 0; dc < 8; dc++) {
            int c = (dc * 16 + hi8) ^ xsw;
            short8 kf0 = *(const short8*)(kr0 + c);
            short8 kf1 = *(const short8*)(kr1 + c);
            s0 = __builtin_amdgcn_mfma_f32_32x32x16_bf16(kf0, qf[dc], s0, 0, 0, 0);
            s1 = __builtin_amdgcn_mfma_f32_32x32x16_bf16(kf1, qf[dc], s1, 0, 0, 0);
        }

        // ---- V: write tile t+1 into v_lds[nxt], issue loads for t+2 ----
        if (t + 1 < NT) {
            *(long*)&v_lds[nxt][vwb]     = rvlo;
            *(long*)&v_lds[nxt][vwb + 8] = rvhi;
            if (t + 2 < NT) {
                int vo = (t + 2) * 64;
                rvlo = *(const long*)(vst + vo);
                rvhi = *(const long*)(vst + vo + 8);
            }
        }

        // ---- online softmax (base 2) ----
        float mx[8];
        #pragma unroll
        for (int i = 0; i < 8; i++)
            mx[i] = fmaxf(fmaxf(s0[i], s0[i+8]), fmaxf(s1[i], s1[i+8]));
        #pragma unroll
        for (int st = 4; st > 0; st >>= 1)
            #pragma unroll
            for (int i = 0; i < st; i++) mx[i] = fmaxf(mx[i], mx[i+st]);
        float pmax = fmaxf(mx[0], __shfl_xor(mx[0], 32));

        if (!__all(pmax - m_q <= 7.f)) {      // base-2: P <= 2^7 = 128 < 448
            float mnew = fmaxf(m_q, pmax);
            float corr = exp2_hw(m_q - mnew);
            l_q *= corr;
            m_q = mnew;
            #pragma unroll
            for (int r = 0; r < 16; r++) {
                float cr = __shfl(corr, (r & 3) + 8 * (r >> 2) + 4 * hi);
                #pragma unroll
                for (int dn = 0; dn < 4; dn++) o_acc[dn][r] *= cr;
            }
        }

        float ls0 = 0.f, ls1 = 0.f, ls2 = 0.f, ls3 = 0.f;
        #pragma unroll
        for (int r = 0; r < 16; r++) {
            float e0 = exp2_hw(s0[r] - m_q);
            float e1 = exp2_hw(s1[r] - m_q);
            s0[r] = e0; s1[r] = e1;
            if (r & 1) { ls1 += e0; ls3 += e1; } else { ls0 += e0; ls2 += e1; }
        }
        float lsum = (ls0 + ls1) + (ls2 + ls3);
        lsum += __shfl_xor(lsum, 32);
        l_q += lsum;

        // ---- pack P -> fp8 + permlane redistribute (r10-verified) ----
        long ap8[4];
        #pragma unroll
        for (int ks = 0; ks < 4; ks++) {
            const f32x16& sN = (ks < 2) ? s0 : s1;
            int rb = (ks & 1) * 8;
            unsigned F0 = cvt_pk_fp8_lo(0u, sN[rb+0], sN[rb+1]);
            F0 = cvt_pk_fp8_hi(F0, sN[rb+2], sN[rb+3]);
            unsigned F1 = cvt_pk_fp8_lo(0u, sN[rb+4], sN[rb+5]);
            F1 = cvt_pk_fp8_hi(F1, sN[rb+6], sN[rb+7]);
            uint2v d01 = __builtin_amdgcn_permlane32_swap(F0, F1, false, false);
            ap8[ks] = (long)(((unsigned long)d01[1] << 32) | (unsigned long)d01[0]);
        }

        // ---- O += P V from fp8 v_lds[cur] ----
        #pragma unroll
        for (int dn = 0; dn < 4; dn++) {
            const unsigned char* vr = &v_lds[cur][(size_t)(dn*32 + lq) * VROW];
            #pragma unroll
            for (int ks = 0; ks < 4; ks++) {
                long vf = *(const long*)(vr + ((ks ^ vsw) << 4) + hi8);
                o_acc[dn] = __builtin_amdgcn_mfma_f32_32x32x16_fp8_fp8(ap8[ks], vf, o_acc[dn], 0, 0, 0);
            }
        }

        // single barrier: drains K DMA (vmcnt) + certifies cur reads done and
        // nxt V writes visible; all write/read buffer pairs disjoint (r9 proof)
        __syncthreads();
    }

    float linv = 1.f / l_q;
    ushort* ob = ot + ((size_t)b * T_ + q0w) * HK + h * KD;
    #pragma unroll
    for (int r = 0; r < 16; r++) {
        int qrow = (r & 3) + 8 * (r >> 2) + 4 * hi;
        float lr_ = __shfl(linv, qrow);
        #pragma unroll
        for (int dn = 0; dn < 4; dn++)
            ob[(size_t)qrow * HK + dn*32 + lq] = f2bf(o_acc[dn][r] * lr_);
    }
}

extern "C" void kernel_launch(void* const* d_in, const int* in_sizes, int n_in,
                              void* d_out, int out_size, void* d_ws, size_t ws_size,
                              hipStream_t stream) {
    const float* x  = (const float*)d_in[0];
    const float* Wq = (const float*)d_in[1];
    const float* Wk = (const float*)d_in[2];
    const float* Wv = (const float*)d_in[3];
    const float* Wu = (const float*)d_in[4];
    const float* bu = (const float*)d_in[5];
    float* out = (float*)d_out;

    const size_t XT  = (size_t)B_ * T_ * KD * 2;
    const size_t WB  = (size_t)HK * KD * 2;
    const size_t BIG = (size_t)B_ * T_ * HK * 2;   // bf16 buffers
    const size_t VSZ = (size_t)B_ * HK * T_;       // fp8 V
    size_t need = XT + 4*WB + 3*BIG + VSZ;
    if (ws_size < need) return;

    char* p = (char*)d_ws;
    ushort* xt  = (ushort*)p;            p += XT;
    ushort* wqb = (ushort*)p;            p += WB;   // wq|wk|wv|wu contiguous
    ushort* wkb = (ushort*)p;            p += WB;
    ushort* wvb = (ushort*)p;            p += WB;
    ushort* wub = (ushort*)p;            p += WB;
    ushort* qtb = (ushort*)p;            p += BIG;
    ushort* ktb = (ushort*)p;            p += BIG;
    unsigned char* vsb = (unsigned char*)p;  p += VSZ;
    ushort* otb = (ushort*)p;            p += BIG;
    (void)wkb; (void)wvb;

    prep_kernel<<<2304, 256, 0, stream>>>(x, Wq, Wk, Wv, Wu, wqb, xt);

    proj_kernel<<<dim3(128, 12), 256, 0, stream>>>(xt, wqb, qtb, ktb, vsb);

    attn32_kernel<<<dim3(256), 512, 0, stream>>>(qtb, ktb, vsb, otb);

    gemm_abT_f32bias<<<dim3(KD/64, T_/64, B_), 256, 0, stream>>>(
        wub, otb, (long)T_*HK, bu, out, (long)KD*T_, KD, T_, HK);
}

// Round 16
// 126.041 us; speedup vs baseline: 1.0499x; 1.0281x over previous
//
#include <hip/hip_runtime.h>
#include <hip/hip_bf16.h>

using short8 = __attribute__((ext_vector_type(8))) short;
using f32x4  = __attribute__((ext_vector_type(4))) float;
using f32x16 = __attribute__((ext_vector_type(16))) float;
using uint2v = __attribute__((ext_vector_type(2))) unsigned;
using float4v = __attribute__((ext_vector_type(4))) float;
using ushort4v = __attribute__((ext_vector_type(4))) ushort;

#define B_  4
#define KD  128      // head dim / model dim k
#define T_  2048
#define H_  8
#define HK  (H_*KD)  // 1024
#define NT  (T_/64)  // 32 KV tiles
#define VROW 72      // padded fp8 V row bytes (odd dword-pair stride -> conflict-free)

__device__ __forceinline__ ushort f2bf(float f) {
    unsigned u = __builtin_bit_cast(unsigned, f);
    u += 0x7fffu + ((u >> 16) & 1u);
    return (ushort)(u >> 16);
}

// raw v_exp_f32: computes 2^x in one instruction (args here are finite, |x| small)
__device__ __forceinline__ float exp2_hw(float x) {
    float r;
    asm("v_exp_f32 %0, %1" : "=v"(r) : "v"(x));
    return r;
}

// packs 2 f32 -> 2 fp8 e4m3 into low / high 16 bits of r (other bits preserved)
__device__ __forceinline__ unsigned cvt_pk_fp8_lo(unsigned old, float a, float b) {
    unsigned r = old;
    asm("v_cvt_pk_fp8_f32 %0, %1, %2" : "+v"(r) : "v"(a), "v"(b));
    return r;
}
__device__ __forceinline__ unsigned cvt_pk_fp8_hi(unsigned old, float a, float b) {
    unsigned r = old;
    asm("v_cvt_pk_fp8_f32 %0, %1, %2 op_sel:[0,0,1]" : "+v"(r) : "v"(a), "v"(b));
    return r;
}

// Fused prep: blocks [0,512) convert the 4 weight mats vectorized x4
// (contiguous dst), blocks [512,768) transpose x [B][KD][T] f32 -> xt bf16.
__global__ __launch_bounds__(256) void prep_kernel(const float* __restrict__ x,
                                                   const float* __restrict__ Wq,
                                                   const float* __restrict__ Wk,
                                                   const float* __restrict__ Wv,
                                                   const float* __restrict__ Wu,
                                                   ushort* __restrict__ wdst,
                                                   ushort* __restrict__ xt) {
    __shared__ float tile[64][65];
    int bx = blockIdx.x;
    if (bx < 512) {
        int i4 = bx * 256 + threadIdx.x;          // vec4 index over 4*HK*KD/4
        const int n1v = (HK * KD) >> 2;           // 32768 vec4 per matrix
        const float* src = (i4 < n1v) ? Wq : (i4 < 2*n1v) ? Wk : (i4 < 3*n1v) ? Wv : Wu;
        float4v v = *(const float4v*)(src + (size_t)(i4 & (n1v - 1)) * 4);
        ushort4v o;
        o[0] = f2bf(v[0]); o[1] = f2bf(v[1]); o[2] = f2bf(v[2]); o[3] = f2bf(v[3]);
        *(ushort4v*)(wdst + (size_t)i4 * 4) = o;
        return;
    }
    int bi = bx - 512;
    int t0 = (bi & 31) * 64;
    int k0 = ((bi >> 5) & 1) * 64;
    int b  = bi >> 6;
    int c  = threadIdx.x & 63;
    int r4 = threadIdx.x >> 6;
    #pragma unroll
    for (int i = 0; i < 16; i++) {
        int k = r4 * 16 + i;
        tile[k][c] = x[((size_t)b * KD + k0 + k) * T_ + t0 + c];
    }
    __syncthreads();
    #pragma unroll
    for (int i = 0; i < 16; i++) {
        int t = r4 * 16 + i;
        xt[((size_t)b * T_ + t0 + t) * KD + k0 + c] = f2bf(tile[c][t]);
    }
}

// Fused projections, packed-store epilogues (r11-verified), XCD-chunked tidb.
// Q scale folds 1/sqrt(128) * log2(e) so attention softmax runs in base 2.
__global__ __launch_bounds__(256, 2) void proj_kernel(const ushort* __restrict__ xt,
                                                      const ushort* __restrict__ wall,
                                                      ushort* __restrict__ qtb,
                                                      ushort* __restrict__ ktb,
                                                      unsigned char* __restrict__ vsb) {
    int bz = blockIdx.y;
    int which = bz >> 2, b = bz & 3;
    int bxr = blockIdx.x;                  // 0..127
    int tidb = (bxr & 7) * 16 + (bxr >> 3);   // XCD chunk swizzle (bijective)
    int lane = threadIdx.x & 63;
    int w    = threadIdx.x >> 6;
    int lq = lane & 31, hi = lane >> 5, hi8 = hi * 8;

    int tt0 = (tidb >> 3) * 128;           // t-tile base (16 tiles)
    int jj0 = (tidb & 7) * 128;            // j-tile base (8 tiles)

    const ushort *a0p, *a1p, *b0p, *b1p;
    int m0, n0;                            // m = D-row base, n = D-col base
    if (which < 2) {
        m0 = jj0 + (w >> 1) * 64;          // rows = j
        n0 = tt0 + (w & 1) * 64;           // cols = t
        const ushort* A  = wall + (size_t)which * (HK * KD);
        const ushort* Bp = xt + (size_t)b * T_ * KD;
        a0p = A  + (size_t)(m0 + lq) * KD + hi8;
        a1p = A  + (size_t)(m0 + 32 + lq) * KD + hi8;
        b0p = Bp + (size_t)(n0 + lq) * KD + hi8;
        b1p = Bp + (size_t)(n0 + 32 + lq) * KD + hi8;
    } else {
        m0 = tt0 + (w >> 1) * 64;          // rows = t
        n0 = jj0 + (w & 1) * 64;           // cols = j
        const ushort* A  = xt + (size_t)b * T_ * KD;
        const ushort* Bp = wall + (size_t)2 * (HK * KD);
        a0p = A  + (size_t)(m0 + lq) * KD + hi8;
        a1p = A  + (size_t)(m0 + 32 + lq) * KD + hi8;
        b0p = Bp + (size_t)(n0 + lq) * KD + hi8;
        b1p = Bp + (size_t)(n0 + 32 + lq) * KD + hi8;
    }

    short8 a0[8], a1[8], b0[8], b1[8];
    #pragma unroll
    for (int kc = 0; kc < 8; kc++) {
        a0[kc] = *(const short8*)(a0p + kc * 16);
        a1[kc] = *(const short8*)(a1p + kc * 16);
        b0[kc] = *(const short8*)(b0p + kc * 16);
        b1[kc] = *(const short8*)(b1p + kc * 16);
    }
    f32x16 acc[2][2] = {};
    #pragma unroll
    for (int kc = 0; kc < 8; kc++) {
        acc[0][0] = __builtin_amdgcn_mfma_f32_32x32x16_bf16(a0[kc], b0[kc], acc[0][0], 0, 0, 0);
        acc[0][1] = __builtin_amdgcn_mfma_f32_32x32x16_bf16(a0[kc], b1[kc], acc[0][1], 0, 0, 0);
        acc[1][0] = __builtin_amdgcn_mfma_f32_32x32x16_bf16(a1[kc], b0[kc], acc[1][0], 0, 0, 0);
        acc[1][1] = __builtin_amdgcn_mfma_f32_32x32x16_bf16(a1[kc], b1[kc], acc[1][1], 0, 0, 0);
    }

    if (which < 2) {
        // Q: 1/sqrt(128) * log2(e)  (base-2 softmax in attn);  K: 1.0
        float scale = which ? 1.f : 0.12751743f;
        ushort* C = (which ? ktb : qtb) + (size_t)b * T_ * HK;
        #pragma unroll
        for (int i = 0; i < 2; i++)
            #pragma unroll
            for (int jj = 0; jj < 2; jj++) {
                int t = n0 + jj*32 + lq;
                #pragma unroll
                for (int qd = 0; qd < 4; qd++) {
                    int jb = m0 + i*32 + 8*qd + 4*hi;
                    const f32x16& a = acc[i][jj];
                    unsigned u0 = (unsigned)f2bf(a[4*qd+0]*scale)
                                | ((unsigned)f2bf(a[4*qd+1]*scale) << 16);
                    unsigned u1 = (unsigned)f2bf(a[4*qd+2]*scale)
                                | ((unsigned)f2bf(a[4*qd+3]*scale) << 16);
                    uint2v uv; uv[0] = u0; uv[1] = u1;
                    *(uint2v*)(C + (size_t)t * HK + jb) = uv;
                }
            }
    } else {
        unsigned char* C = vsb + (size_t)b * HK * T_;
        #pragma unroll
        for (int i = 0; i < 2; i++)
            #pragma unroll
            for (int jj = 0; jj < 2; jj++) {
                int j = n0 + jj*32 + lq;
                #pragma unroll
                for (int qd = 0; qd < 4; qd++) {
                    int tb = m0 + i*32 + 8*qd + 4*hi;
                    const f32x16& a = acc[i][jj];
                    unsigned dw = cvt_pk_fp8_lo(0u, a[4*qd+0], a[4*qd+1]);
                    dw = cvt_pk_fp8_hi(dw, a[4*qd+2], a[4*qd+3]);
                    *(unsigned*)(C + (size_t)j * T_ + tb) = dw;
                }
            }
    }
}

// out[m][n] = sum_k A[m][k]*B[n][k] + bias[m];  f32 out  (r6-verified version)
__global__ __launch_bounds__(256) void gemm_abT_f32bias(const ushort* __restrict__ A,
                                                        const ushort* __restrict__ B, long sB,
                                                        const float* __restrict__ bias,
                                                        float* __restrict__ C, long sC,
                                                        int M, int N, int Kd) {
    int b = blockIdx.z;
    B += (long)b * sB;  C += (long)b * sC;
    int lane = threadIdx.x & 63;
    int w    = threadIdx.x >> 6;
    int lr = lane & 15, lg = lane >> 4;
    int m0 = blockIdx.x * 64 + (w >> 1) * 32;
    int n0 = blockIdx.y * 64 + (w & 1) * 32;

    f32x4 acc[2][2] = {};
    #pragma unroll 4
    for (int k0 = 0; k0 < Kd; k0 += 32) {
        short8 af[2], bf[2];
        #pragma unroll
        for (int i = 0; i < 2; i++)
            af[i] = *(const short8*)(A + (long)(m0 + i*16 + lr) * Kd + k0 + lg*8);
        #pragma unroll
        for (int j = 0; j < 2; j++)
            bf[j] = *(const short8*)(B + (long)(n0 + j*16 + lr) * Kd + k0 + lg*8);
        #pragma unroll
        for (int i = 0; i < 2; i++)
            #pragma unroll
            for (int j = 0; j < 2; j++)
                acc[i][j] = __builtin_amdgcn_mfma_f32_16x16x32_bf16(af[i], bf[j], acc[i][j], 0, 0, 0);
    }
    #pragma unroll
    for (int i = 0; i < 2; i++)
        #pragma unroll
        for (int j = 0; j < 2; j++)
            #pragma unroll
            for (int r = 0; r < 4; r++) {
                int m = m0 + i*16 + lg*4 + r;
                int n = n0 + j*16 + lr;
                C[(long)m * N + n] = acc[i][j][r] + bias[m];
            }
}

// Flash attention (r13-verified, best known: 74.2us): 8 waves x 32 queries,
// K bf16 LDS (XOR swizzle) + V fp8 LDS (72B pad), both double-buffered,
// reg-staged async; swapped QK^T bf16; base-2 softmax via v_exp_f32 (Q
// pre-scaled by log2e/sqrt(128)); fp8 P cvt_pk+permlane; PV fp8 MFMA; THR=7.
__global__ __launch_bounds__(512, 2) void attn32_kernel(const ushort* __restrict__ qt,
                                                        const ushort* __restrict__ kt,
                                                        const unsigned char* __restrict__ vs,
                                                        ushort* __restrict__ ot) {
    int f = blockIdx.x;
    int xcd = f & 7, u = f >> 3;
    int qt8 = u & 7, gh = u >> 3;
    int g = xcd + 8 * gh;                  // 0..31 == h + 8*b
    int h = g & 7, b = g >> 3;
    int w    = threadIdx.x >> 6;
    int lane = threadIdx.x & 63;
    int lq = lane & 31, hi = lane >> 5;
    int hi8 = hi * 8;
    int q0w = qt8 * 256 + w * 32;

    __shared__ __align__(16) ushort k_lds[2][64 * 128];
    __shared__ __align__(16) unsigned char v_lds[2][128 * VROW];

    int tid  = threadIdx.x;
    int krow = tid >> 3, kcol = (tid & 7) << 4;
    const ushort* kst = kt + ((size_t)b * T_ + krow) * HK + h * KD + kcol;
    int kwi = krow * 128 + (kcol ^ ((krow & 7) << 3));
    // V staging: 512 threads x 16B; row = d (0..127), 16B chunk = tid&3
    int vrow = tid >> 2, vc16 = (tid & 3) << 4;
    const unsigned char* vst = vs + ((size_t)b * HK + h * KD + vrow) * T_ + vc16;
    int vwb = vrow * VROW + ((((vc16 >> 4) ^ (vrow & 3))) << 4);

    const ushort* qbase = qt + ((size_t)b * T_ + q0w + lq) * HK + h * KD + hi8;

    short8 qf[8];
    #pragma unroll
    for (int dc = 0; dc < 8; dc++)
        qf[dc] = *(const short8*)(qbase + dc * 16);

    short8 rk0 = *(const short8*)(kst);
    short8 rk1 = *(const short8*)(kst + 8);
    long rvlo = *(const long*)(vst);
    long rvhi = *(const long*)(vst + 8);
    *(short8*)&k_lds[0][kwi]     = rk0;
    *(short8*)&k_lds[0][kwi ^ 8] = rk1;
    *(long*)&v_lds[0][vwb]       = rvlo;
    *(long*)&v_lds[0][vwb + 8]   = rvhi;
    rk0 = *(const short8*)(kst + (size_t)64 * HK);
    rk1 = *(const short8*)(kst + (size_t)64 * HK + 8);
    rvlo = *(const long*)(vst + 64);
    rvhi = *(const long*)(vst + 64 + 8);
    __syncthreads();

    f32x16 o_acc[4] = {};
    float m_q = -1e30f, l_q = 0.f;
    const int xsw = (lq & 7) << 3;      // K read swizzle (bf16 elems)
    const int vsw = lq & 3;             // V read chunk swizzle

    for (int t = 0; t < NT; ++t) {
        const int cur = t & 1;
        f32x16 s0 = {}, s1 = {};
        const ushort* kr0 = &k_lds[cur][(size_t)lq * 128];
        const ushort* kr1 = &k_lds[cur][(size_t)(32 + lq) * 128];
        #pragma unroll
        for (int dc = 0; dc < 8; dc++) {
            int c = (dc * 16 + hi8) ^ xsw;
            short8 kf0 = *(const short8*)(kr0 + c);
            short8 kf1 = *(const short8*)(kr1 + c);
            s0 = __builtin_amdgcn_mfma_f32_32x32x16_bf16(kf0, qf[dc], s0, 0, 0, 0);
            s1 = __builtin_amdgcn_mfma_f32_32x32x16_bf16(kf1, qf[dc], s1, 0, 0, 0);
        }

        float mx[8];
        #pragma unroll
        for (int i = 0; i < 8; i++)
            mx[i] = fmaxf(fmaxf(s0[i], s0[i+8]), fmaxf(s1[i], s1[i+8]));
        #pragma unroll
        for (int st = 4; st > 0; st >>= 1)
            #pragma unroll
            for (int i = 0; i < st; i++) mx[i] = fmaxf(mx[i], mx[i+st]);
        float pmax = fmaxf(mx[0], __shfl_xor(mx[0], 32));

        if (!__all(pmax - m_q <= 7.f)) {      // base-2: P <= 2^7 = 128 < 448
            float mnew = fmaxf(m_q, pmax);
            float corr = exp2_hw(m_q - mnew);
            l_q *= corr;
            m_q = mnew;
            #pragma unroll
            for (int r = 0; r < 16; r++) {
                float cr = __shfl(corr, (r & 3) + 8 * (r >> 2) + 4 * hi);
                #pragma unroll
                for (int dn = 0; dn < 4; dn++) o_acc[dn][r] *= cr;
            }
        }

        float ls0 = 0.f, ls1 = 0.f, ls2 = 0.f, ls3 = 0.f;
        #pragma unroll
        for (int r = 0; r < 16; r++) {
            float e0 = exp2_hw(s0[r] - m_q);
            float e1 = exp2_hw(s1[r] - m_q);
            s0[r] = e0; s1[r] = e1;
            if (r & 1) { ls1 += e0; ls3 += e1; } else { ls0 += e0; ls2 += e1; }
        }
        float lsum = (ls0 + ls1) + (ls2 + ls3);
        lsum += __shfl_xor(lsum, 32);
        l_q += lsum;

        // ---- pack P -> fp8 + permlane redistribute (r10-verified) ----
        long ap8[4];
        #pragma unroll
        for (int ks = 0; ks < 4; ks++) {
            const f32x16& sN = (ks < 2) ? s0 : s1;
            int rb = (ks & 1) * 8;
            unsigned F0 = cvt_pk_fp8_lo(0u, sN[rb+0], sN[rb+1]);
            F0 = cvt_pk_fp8_hi(F0, sN[rb+2], sN[rb+3]);
            unsigned F1 = cvt_pk_fp8_lo(0u, sN[rb+4], sN[rb+5]);
            F1 = cvt_pk_fp8_hi(F1, sN[rb+6], sN[rb+7]);
            uint2v d01 = __builtin_amdgcn_permlane32_swap(F0, F1, false, false);
            ap8[ks] = (long)(((unsigned long)d01[1] << 32) | (unsigned long)d01[0]);
        }

        // ---- O += P V from fp8 v_lds[cur] ----
        #pragma unroll
        for (int dn = 0; dn < 4; dn++) {
            const unsigned char* vr = &v_lds[cur][(size_t)(dn*32 + lq) * VROW];
            #pragma unroll
            for (int ks = 0; ks < 4; ks++) {
                long vf = *(const long*)(vr + ((ks ^ vsw) << 4) + hi8);
                o_acc[dn] = __builtin_amdgcn_mfma_f32_32x32x16_fp8_fp8(ap8[ks], vf, o_acc[dn], 0, 0, 0);
            }
        }

        __syncthreads();
        if (t + 1 < NT) {
            const int nxt = cur ^ 1;
            *(short8*)&k_lds[nxt][kwi]     = rk0;
            *(short8*)&k_lds[nxt][kwi ^ 8] = rk1;
            *(long*)&v_lds[nxt][vwb]       = rvlo;
            *(long*)&v_lds[nxt][vwb + 8]   = rvhi;
            if (t + 2 < NT) {
                size_t ko = (size_t)(t + 2) * 64 * HK;
                int    vo = (t + 2) * 64;
                rk0 = *(const short8*)(kst + ko);
                rk1 = *(const short8*)(kst + ko + 8);
                rvlo = *(const long*)(vst + vo);
                rvhi = *(const long*)(vst + vo + 8);
            }
            __syncthreads();
        }
    }

    float linv = 1.f / l_q;
    ushort* ob = ot + ((size_t)b * T_ + q0w) * HK + h * KD;
    #pragma unroll
    for (int r = 0; r < 16; r++) {
        int qrow = (r & 3) + 8 * (r >> 2) + 4 * hi;
        float lr_ = __shfl(linv, qrow);
        #pragma unroll
        for (int dn = 0; dn < 4; dn++)
            ob[(size_t)qrow * HK + dn*32 + lq] = f2bf(o_acc[dn][r] * lr_);
    }
}

extern "C" void kernel_launch(void* const* d_in, const int* in_sizes, int n_in,
                              void* d_out, int out_size, void* d_ws, size_t ws_size,
                              hipStream_t stream) {
    const float* x  = (const float*)d_in[0];
    const float* Wq = (const float*)d_in[1];
    const float* Wk = (const float*)d_in[2];
    const float* Wv = (const float*)d_in[3];
    const float* Wu = (const float*)d_in[4];
    const float* bu = (const float*)d_in[5];
    float* out = (float*)d_out;

    const size_t XT  = (size_t)B_ * T_ * KD * 2;
    const size_t WB  = (size_t)HK * KD * 2;
    const size_t BIG = (size_t)B_ * T_ * HK * 2;   // bf16 buffers
    const size_t VSZ = (size_t)B_ * HK * T_;       // fp8 V
    size_t need = XT + 4*WB + 3*BIG + VSZ;
    if (ws_size < need) return;

    char* p = (char*)d_ws;
    ushort* xt  = (ushort*)p;            p += XT;
    ushort* wqb = (ushort*)p;            p += WB;   // wq|wk|wv|wu contiguous
    ushort* wkb = (ushort*)p;            p += WB;
    ushort* wvb = (ushort*)p;            p += WB;
    ushort* wub = (ushort*)p;            p += WB;
    ushort* qtb = (ushort*)p;            p += BIG;
    ushort* ktb = (ushort*)p;            p += BIG;
    unsigned char* vsb = (unsigned char*)p;  p += VSZ;
    ushort* otb = (ushort*)p;            p += BIG;
    (void)wkb; (void)wvb;

    prep_kernel<<<768, 256, 0, stream>>>(x, Wq, Wk, Wv, Wu, wqb, xt);

    proj_kernel<<<dim3(128, 12), 256, 0, stream>>>(xt, wqb, qtb, ktb, vsb);

    attn32_kernel<<<dim3(256), 512, 0, stream>>>(qtb, ktb, vsb, otb);

    gemm_abT_f32bias<<<dim3(KD/64, T_/64, B_), 256, 0, stream>>>(
        wub, otb, (long)T_*HK, bu, out, (long)KD*T_, KD, T_, HK);
}

// Round 17
// 119.198 us; speedup vs baseline: 1.1102x; 1.0574x over previous
//
#include <hip/hip_runtime.h>
#include <hip/hip_bf16.h>

using short8 = __attribute__((ext_vector_type(8))) short;
using f32x4  = __attribute__((ext_vector_type(4))) float;
using f32x16 = __attribute__((ext_vector_type(16))) float;
using uint2v = __attribute__((ext_vector_type(2))) unsigned;
using float4v = __attribute__((ext_vector_type(4))) float;
using ushort4v = __attribute__((ext_vector_type(4))) ushort;

#define B_  4
#define KD  128      // head dim / model dim k
#define T_  2048
#define H_  8
#define HK  (H_*KD)  // 1024
#define NT  (T_/64)  // 32 KV tiles
#define VROW 72      // padded fp8 V row bytes (odd dword-pair stride -> conflict-free)

__device__ __forceinline__ ushort f2bf(float f) {
    unsigned u = __builtin_bit_cast(unsigned, f);
    u += 0x7fffu + ((u >> 16) & 1u);
    return (ushort)(u >> 16);
}

// raw v_exp_f32: computes 2^x in one instruction (args here are finite, |x| small)
__device__ __forceinline__ float exp2_hw(float x) {
    float r;
    asm("v_exp_f32 %0, %1" : "=v"(r) : "v"(x));
    return r;
}

// packs 2 f32 -> 2 fp8 e4m3 into low / high 16 bits of r (other bits preserved)
__device__ __forceinline__ unsigned cvt_pk_fp8_lo(unsigned old, float a, float b) {
    unsigned r = old;
    asm("v_cvt_pk_fp8_f32 %0, %1, %2" : "+v"(r) : "v"(a), "v"(b));
    return r;
}
__device__ __forceinline__ unsigned cvt_pk_fp8_hi(unsigned old, float a, float b) {
    unsigned r = old;
    asm("v_cvt_pk_fp8_f32 %0, %1, %2 op_sel:[0,0,1]" : "+v"(r) : "v"(a), "v"(b));
    return r;
}

// Fused prep: blocks [0,512) convert the 4 weight mats vectorized x4
// (contiguous dst), blocks [512,768) transpose x [B][KD][T] f32 -> xt bf16.
__global__ __launch_bounds__(256) void prep_kernel(const float* __restrict__ x,
                                                   const float* __restrict__ Wq,
                                                   const float* __restrict__ Wk,
                                                   const float* __restrict__ Wv,
                                                   const float* __restrict__ Wu,
                                                   ushort* __restrict__ wdst,
                                                   ushort* __restrict__ xt) {
    __shared__ float tile[64][65];
    int bx = blockIdx.x;
    if (bx < 512) {
        int i4 = bx * 256 + threadIdx.x;          // vec4 index over 4*HK*KD/4
        const int n1v = (HK * KD) >> 2;           // 32768 vec4 per matrix
        const float* src = (i4 < n1v) ? Wq : (i4 < 2*n1v) ? Wk : (i4 < 3*n1v) ? Wv : Wu;
        float4v v = *(const float4v*)(src + (size_t)(i4 & (n1v - 1)) * 4);
        ushort4v o;
        o[0] = f2bf(v[0]); o[1] = f2bf(v[1]); o[2] = f2bf(v[2]); o[3] = f2bf(v[3]);
        *(ushort4v*)(wdst + (size_t)i4 * 4) = o;
        return;
    }
    int bi = bx - 512;
    int t0 = (bi & 31) * 64;
    int k0 = ((bi >> 5) & 1) * 64;
    int b  = bi >> 6;
    int c  = threadIdx.x & 63;
    int r4 = threadIdx.x >> 6;
    #pragma unroll
    for (int i = 0; i < 16; i++) {
        int k = r4 * 16 + i;
        tile[k][c] = x[((size_t)b * KD + k0 + k) * T_ + t0 + c];
    }
    __syncthreads();
    #pragma unroll
    for (int i = 0; i < 16; i++) {
        int t = r4 * 16 + i;
        xt[((size_t)b * T_ + t0 + t) * KD + k0 + c] = f2bf(tile[c][t]);
    }
}

// Fused projections (r10-verified variant: A=xt for Q/K, scalar stores, no
// tidb swizzle). grid (128, 12); which = y>>2 (0=Q,1=K,2=V), b = y&3.
// Q scale folds 1/sqrt(128) * log2(e) so attention softmax runs in base 2.
__global__ __launch_bounds__(256, 2) void proj_kernel(const ushort* __restrict__ xt,
                                                      const ushort* __restrict__ wall,
                                                      ushort* __restrict__ qtb,
                                                      ushort* __restrict__ ktb,
                                                      unsigned char* __restrict__ vsb) {
    int bz = blockIdx.y;
    int which = bz >> 2, b = bz & 3;
    int tidb = blockIdx.x;                 // 0..127
    const ushort *A, *Bp;
    void* Cv;
    int N, m0, n0;
    float scale = 1.f;
    if (which < 2) {
        m0 = (tidb >> 3) * 128;            // t-tile (16)
        n0 = (tidb & 7) * 128;             // j-tile (8)
        A  = xt + (size_t)b * T_ * KD;
        Bp = wall + (size_t)which * (HK * KD);
        Cv = (which ? ktb : qtb) + (size_t)b * T_ * HK;
        N  = HK;
        if (which == 0) scale = 0.12751743f;   // 1/sqrt(128) * log2(e)
    } else {
        m0 = (tidb >> 4) * 128;            // j-tile (8)
        n0 = (tidb & 15) * 128;            // t-tile (16)
        A  = wall + (size_t)2 * (HK * KD);
        Bp = xt + (size_t)b * T_ * KD;
        Cv = vsb + (size_t)b * HK * T_;
        N  = T_;
    }
    int lane = threadIdx.x & 63;
    int w    = threadIdx.x >> 6;
    int lq = lane & 31, hi = lane >> 5, hi8 = hi * 8;
    m0 += (w >> 1) * 64;
    n0 += (w & 1) * 64;

    const ushort* a0p = A  + (size_t)(m0 + lq) * KD + hi8;
    const ushort* a1p = A  + (size_t)(m0 + 32 + lq) * KD + hi8;
    const ushort* b0p = Bp + (size_t)(n0 + lq) * KD + hi8;
    const ushort* b1p = Bp + (size_t)(n0 + 32 + lq) * KD + hi8;

    short8 a0[8], a1[8], b0[8], b1[8];
    #pragma unroll
    for (int kc = 0; kc < 8; kc++) {
        a0[kc] = *(const short8*)(a0p + kc * 16);
        a1[kc] = *(const short8*)(a1p + kc * 16);
        b0[kc] = *(const short8*)(b0p + kc * 16);
        b1[kc] = *(const short8*)(b1p + kc * 16);
    }
    f32x16 acc[2][2] = {};
    #pragma unroll
    for (int kc = 0; kc < 8; kc++) {
        acc[0][0] = __builtin_amdgcn_mfma_f32_32x32x16_bf16(a0[kc], b0[kc], acc[0][0], 0, 0, 0);
        acc[0][1] = __builtin_amdgcn_mfma_f32_32x32x16_bf16(a0[kc], b1[kc], acc[0][1], 0, 0, 0);
        acc[1][0] = __builtin_amdgcn_mfma_f32_32x32x16_bf16(a1[kc], b0[kc], acc[1][0], 0, 0, 0);
        acc[1][1] = __builtin_amdgcn_mfma_f32_32x32x16_bf16(a1[kc], b1[kc], acc[1][1], 0, 0, 0);
    }
    if (which < 2) {
        ushort* C = (ushort*)Cv;
        #pragma unroll
        for (int i = 0; i < 2; i++)
            #pragma unroll
            for (int j = 0; j < 2; j++)
                #pragma unroll
                for (int r = 0; r < 16; r++) {
                    int m = m0 + i*32 + (r & 3) + 8 * (r >> 2) + 4 * hi;
                    int n = n0 + j*32 + lq;
                    C[(size_t)m * N + n] = f2bf(acc[i][j][r] * scale);
                }
    } else {
        unsigned char* C = (unsigned char*)Cv;
        #pragma unroll
        for (int i = 0; i < 2; i++)
            #pragma unroll
            for (int j = 0; j < 2; j++)
                #pragma unroll
                for (int r = 0; r < 16; r++) {
                    int m = m0 + i*32 + (r & 3) + 8 * (r >> 2) + 4 * hi;
                    int n = n0 + j*32 + lq;
                    float v = acc[i][j][r];
                    C[(size_t)m * N + n] = (unsigned char)(cvt_pk_fp8_lo(0u, v, v) & 0xffu);
                }
    }
}

// out[m][n] = sum_k A[m][k]*B[n][k] + bias[m];  f32 out  (r6-verified version)
__global__ __launch_bounds__(256) void gemm_abT_f32bias(const ushort* __restrict__ A,
                                                        const ushort* __restrict__ B, long sB,
                                                        const float* __restrict__ bias,
                                                        float* __restrict__ C, long sC,
                                                        int M, int N, int Kd) {
    int b = blockIdx.z;
    B += (long)b * sB;  C += (long)b * sC;
    int lane = threadIdx.x & 63;
    int w    = threadIdx.x >> 6;
    int lr = lane & 15, lg = lane >> 4;
    int m0 = blockIdx.x * 64 + (w >> 1) * 32;
    int n0 = blockIdx.y * 64 + (w & 1) * 32;

    f32x4 acc[2][2] = {};
    #pragma unroll 4
    for (int k0 = 0; k0 < Kd; k0 += 32) {
        short8 af[2], bf[2];
        #pragma unroll
        for (int i = 0; i < 2; i++)
            af[i] = *(const short8*)(A + (long)(m0 + i*16 + lr) * Kd + k0 + lg*8);
        #pragma unroll
        for (int j = 0; j < 2; j++)
            bf[j] = *(const short8*)(B + (long)(n0 + j*16 + lr) * Kd + k0 + lg*8);
        #pragma unroll
        for (int i = 0; i < 2; i++)
            #pragma unroll
            for (int j = 0; j < 2; j++)
                acc[i][j] = __builtin_amdgcn_mfma_f32_16x16x32_bf16(af[i], bf[j], acc[i][j], 0, 0, 0);
    }
    #pragma unroll
    for (int i = 0; i < 2; i++)
        #pragma unroll
        for (int j = 0; j < 2; j++)
            #pragma unroll
            for (int r = 0; r < 4; r++) {
                int m = m0 + i*16 + lg*4 + r;
                int n = n0 + j*16 + lr;
                C[(long)m * N + n] = acc[i][j][r] + bias[m];
            }
}

// Flash attention (r13-verified, best known: 74.2us): 8 waves x 32 queries,
// K bf16 LDS (XOR swizzle) + V fp8 LDS (72B pad), both double-buffered,
// reg-staged async; swapped QK^T bf16; base-2 softmax via v_exp_f32 (Q
// pre-scaled by log2e/sqrt(128)); fp8 P cvt_pk+permlane; PV fp8 MFMA; THR=7.
__global__ __launch_bounds__(512, 2) void attn32_kernel(const ushort* __restrict__ qt,
                                                        const ushort* __restrict__ kt,
                                                        const unsigned char* __restrict__ vs,
                                                        ushort* __restrict__ ot) {
    int f = blockIdx.x;
    int xcd = f & 7, u = f >> 3;
    int qt8 = u & 7, gh = u >> 3;
    int g = xcd + 8 * gh;                  // 0..31 == h + 8*b
    int h = g & 7, b = g >> 3;
    int w    = threadIdx.x >> 6;
    int lane = threadIdx.x & 63;
    int lq = lane & 31, hi = lane >> 5;
    int hi8 = hi * 8;
    int q0w = qt8 * 256 + w * 32;

    __shared__ __align__(16) ushort k_lds[2][64 * 128];
    __shared__ __align__(16) unsigned char v_lds[2][128 * VROW];

    int tid  = threadIdx.x;
    int krow = tid >> 3, kcol = (tid & 7) << 4;
    const ushort* kst = kt + ((size_t)b * T_ + krow) * HK + h * KD + kcol;
    int kwi = krow * 128 + (kcol ^ ((krow & 7) << 3));
    // V staging: 512 threads x 16B; row = d (0..127), 16B chunk = tid&3
    int vrow = tid >> 2, vc16 = (tid & 3) << 4;
    const unsigned char* vst = vs + ((size_t)b * HK + h * KD + vrow) * T_ + vc16;
    int vwb = vrow * VROW + ((((vc16 >> 4) ^ (vrow & 3))) << 4);

    const ushort* qbase = qt + ((size_t)b * T_ + q0w + lq) * HK + h * KD + hi8;

    short8 qf[8];
    #pragma unroll
    for (int dc = 0; dc < 8; dc++)
        qf[dc] = *(const short8*)(qbase + dc * 16);

    short8 rk0 = *(const short8*)(kst);
    short8 rk1 = *(const short8*)(kst + 8);
    long rvlo = *(const long*)(vst);
    long rvhi = *(const long*)(vst + 8);
    *(short8*)&k_lds[0][kwi]     = rk0;
    *(short8*)&k_lds[0][kwi ^ 8] = rk1;
    *(long*)&v_lds[0][vwb]       = rvlo;
    *(long*)&v_lds[0][vwb + 8]   = rvhi;
    rk0 = *(const short8*)(kst + (size_t)64 * HK);
    rk1 = *(const short8*)(kst + (size_t)64 * HK + 8);
    rvlo = *(const long*)(vst + 64);
    rvhi = *(const long*)(vst + 64 + 8);
    __syncthreads();

    f32x16 o_acc[4] = {};
    float m_q = -1e30f, l_q = 0.f;
    const int xsw = (lq & 7) << 3;      // K read swizzle (bf16 elems)
    const int vsw = lq & 3;             // V read chunk swizzle

    for (int t = 0; t < NT; ++t) {
        const int cur = t & 1;
        f32x16 s0 = {}, s1 = {};
        const ushort* kr0 = &k_lds[cur][(size_t)lq * 128];
        const ushort* kr1 = &k_lds[cur][(size_t)(32 + lq) * 128];
        #pragma unroll
        for (int dc = 0; dc < 8; dc++) {
            int c = (dc * 16 + hi8) ^ xsw;
            short8 kf0 = *(const short8*)(kr0 + c);
            short8 kf1 = *(const short8*)(kr1 + c);
            s0 = __builtin_amdgcn_mfma_f32_32x32x16_bf16(kf0, qf[dc], s0, 0, 0, 0);
            s1 = __builtin_amdgcn_mfma_f32_32x32x16_bf16(kf1, qf[dc], s1, 0, 0, 0);
        }

        float mx[8];
        #pragma unroll
        for (int i = 0; i < 8; i++)
            mx[i] = fmaxf(fmaxf(s0[i], s0[i+8]), fmaxf(s1[i], s1[i+8]));
        #pragma unroll
        for (int st = 4; st > 0; st >>= 1)
            #pragma unroll
            for (int i = 0; i < st; i++) mx[i] = fmaxf(mx[i], mx[i+st]);
        float pmax = fmaxf(mx[0], __shfl_xor(mx[0], 32));

        if (!__all(pmax - m_q <= 7.f)) {      // base-2: P <= 2^7 = 128 < 448
            float mnew = fmaxf(m_q, pmax);
            float corr = exp2_hw(m_q - mnew);
            l_q *= corr;
            m_q = mnew;
            #pragma unroll
            for (int r = 0; r < 16; r++) {
                float cr = __shfl(corr, (r & 3) + 8 * (r >> 2) + 4 * hi);
                #pragma unroll
                for (int dn = 0; dn < 4; dn++) o_acc[dn][r] *= cr;
            }
        }

        float ls0 = 0.f, ls1 = 0.f, ls2 = 0.f, ls3 = 0.f;
        #pragma unroll
        for (int r = 0; r < 16; r++) {
            float e0 = exp2_hw(s0[r] - m_q);
            float e1 = exp2_hw(s1[r] - m_q);
            s0[r] = e0; s1[r] = e1;
            if (r & 1) { ls1 += e0; ls3 += e1; } else { ls0 += e0; ls2 += e1; }
        }
        float lsum = (ls0 + ls1) + (ls2 + ls3);
        lsum += __shfl_xor(lsum, 32);
        l_q += lsum;

        // ---- pack P -> fp8 + permlane redistribute (r10-verified) ----
        long ap8[4];
        #pragma unroll
        for (int ks = 0; ks < 4; ks++) {
            const f32x16& sN = (ks < 2) ? s0 : s1;
            int rb = (ks & 1) * 8;
            unsigned F0 = cvt_pk_fp8_lo(0u, sN[rb+0], sN[rb+1]);
            F0 = cvt_pk_fp8_hi(F0, sN[rb+2], sN[rb+3]);
            unsigned F1 = cvt_pk_fp8_lo(0u, sN[rb+4], sN[rb+5]);
            F1 = cvt_pk_fp8_hi(F1, sN[rb+6], sN[rb+7]);
            uint2v d01 = __builtin_amdgcn_permlane32_swap(F0, F1, false, false);
            ap8[ks] = (long)(((unsigned long)d01[1] << 32) | (unsigned long)d01[0]);
        }

        // ---- O += P V from fp8 v_lds[cur] ----
        #pragma unroll
        for (int dn = 0; dn < 4; dn++) {
            const unsigned char* vr = &v_lds[cur][(size_t)(dn*32 + lq) * VROW];
            #pragma unroll
            for (int ks = 0; ks < 4; ks++) {
                long vf = *(const long*)(vr + ((ks ^ vsw) << 4) + hi8);
                o_acc[dn] = __builtin_amdgcn_mfma_f32_32x32x16_fp8_fp8(ap8[ks], vf, o_acc[dn], 0, 0, 0);
            }
        }

        __syncthreads();
        if (t + 1 < NT) {
            const int nxt = cur ^ 1;
            *(short8*)&k_lds[nxt][kwi]     = rk0;
            *(short8*)&k_lds[nxt][kwi ^ 8] = rk1;
            *(long*)&v_lds[nxt][vwb]       = rvlo;
            *(long*)&v_lds[nxt][vwb + 8]   = rvhi;
            if (t + 2 < NT) {
                size_t ko = (size_t)(t + 2) * 64 * HK;
                int    vo = (t + 2) * 64;
                rk0 = *(const short8*)(kst + ko);
                rk1 = *(const short8*)(kst + ko + 8);
                rvlo = *(const long*)(vst + vo);
                rvhi = *(const long*)(vst + vo + 8);
            }
            __syncthreads();
        }
    }

    float linv = 1.f / l_q;
    ushort* ob = ot + ((size_t)b * T_ + q0w) * HK + h * KD;
    #pragma unroll
    for (int r = 0; r < 16; r++) {
        int qrow = (r & 3) + 8 * (r >> 2) + 4 * hi;
        float lr_ = __shfl(linv, qrow);
        #pragma unroll
        for (int dn = 0; dn < 4; dn++)
            ob[(size_t)qrow * HK + dn*32 + lq] = f2bf(o_acc[dn][r] * lr_);
    }
}

extern "C" void kernel_launch(void* const* d_in, const int* in_sizes, int n_in,
                              void* d_out, int out_size, void* d_ws, size_t ws_size,
                              hipStream_t stream) {
    const float* x  = (const float*)d_in[0];
    const float* Wq = (const float*)d_in[1];
    const float* Wk = (const float*)d_in[2];
    const float* Wv = (const float*)d_in[3];
    const float* Wu = (const float*)d_in[4];
    const float* bu = (const float*)d_in[5];
    float* out = (float*)d_out;

    const size_t XT  = (size_t)B_ * T_ * KD * 2;
    const size_t WB  = (size_t)HK * KD * 2;
    const size_t BIG = (size_t)B_ * T_ * HK * 2;   // bf16 buffers
    const size_t VSZ = (size_t)B_ * HK * T_;       // fp8 V
    size_t need = XT + 4*WB + 3*BIG + VSZ;
    if (ws_size < need) return;

    char* p = (char*)d_ws;
    ushort* xt  = (ushort*)p;            p += XT;
    ushort* wqb = (ushort*)p;            p += WB;   // wq|wk|wv|wu contiguous
    ushort* wkb = (ushort*)p;            p += WB;
    ushort* wvb = (ushort*)p;            p += WB;
    ushort* wub = (ushort*)p;            p += WB;
    ushort* qtb = (ushort*)p;            p += BIG;
    ushort* ktb = (ushort*)p;            p += BIG;
    unsigned char* vsb = (unsigned char*)p;  p += VSZ;
    ushort* otb = (ushort*)p;            p += BIG;
    (void)wkb; (void)wvb;

    prep_kernel<<<768, 256, 0, stream>>>(x, Wq, Wk, Wv, Wu, wqb, xt);

    proj_kernel<<<dim3(128, 12), 256, 0, stream>>>(xt, wqb, qtb, ktb, vsb);

    attn32_kernel<<<dim3(256), 512, 0, stream>>>(qtb, ktb, vsb, otb);

    gemm_abT_f32bias<<<dim3(KD/64, T_/64, B_), 256, 0, stream>>>(
        wub, otb, (long)T_*HK, bu, out, (long)KD*T_, KD, T_, HK);
}